// Round 1
// baseline (102.995 us; speedup 1.0000x reference)
//
#include <hip/hip_runtime.h>

// Problem constants (match reference)
#define BB 2048   // batch
#define DD 512    // dim
#define RR 32     // relations

// Main-kernel tiling
#define NCHUNK 16            // e-chunks per relation
#define EC (DD / NCHUNK)     // 32 e's per chunk
#define NWAVE 4              // 256 threads
#define EPW (EC / NWAVE)     // 8 e's per wave
#define ST 64                // samples per LDS tile
#define SB 8                 // samples per register pass

// ws layout (32-bit words)
#define WS_OFFS 0            // int offs[RR+1]
#define WS_ORDER 64          // int order[BB]
#define WS_BIAS (64 + BB)    // float biassum[RR]

__global__ void k_bias(const float* __restrict__ b, float* __restrict__ ws_bias) {
    int r = blockIdx.x;
    int tid = threadIdx.x;
    float v = b[r * DD + tid] + b[r * DD + tid + 256];
    #pragma unroll
    for (int off = 32; off; off >>= 1) v += __shfl_down(v, off);
    __shared__ float red[NWAVE];
    int wave = tid >> 6, lane = tid & 63;
    if (lane == 0) red[wave] = v;
    __syncthreads();
    if (tid == 0) ws_bias[r] = red[0] + red[1] + red[2] + red[3];
}

__global__ void k_bucket(const int* __restrict__ rel,
                         const float* __restrict__ ws_bias,
                         int* __restrict__ offs, int* __restrict__ order,
                         float* __restrict__ out) {
    __shared__ int cnt[RR], cur[RR];
    __shared__ float bs[RR];
    int tid = threadIdx.x;
    if (tid < RR) { cnt[tid] = 0; bs[tid] = ws_bias[tid]; }
    __syncthreads();
    for (int i = tid; i < BB; i += 256) atomicAdd(&cnt[rel[i]], 1);
    __syncthreads();
    if (tid == 0) {
        int acc = 0;
        for (int r = 0; r < RR; r++) { int c = cnt[r]; cur[r] = acc; offs[r] = acc; acc += c; }
        offs[RR] = acc;
    }
    __syncthreads();
    for (int i = tid; i < BB; i += 256) {
        int r = rel[i];
        int pos = atomicAdd(&cur[r], 1);
        order[pos] = i;
        out[i] = bs[r];          // init output with relation bias-sum
    }
}

__launch_bounds__(256)
__global__ void k_main(const float* __restrict__ head,
                       const float* __restrict__ tail,
                       const float* __restrict__ W,
                       const int* __restrict__ offs,
                       const int* __restrict__ order,
                       float* __restrict__ out) {
    const int bid = blockIdx.x;
    const int r = bid >> 4;              // NCHUNK = 16
    const int c = bid & (NCHUNK - 1);
    const int e0 = c * EC;
    const int start = offs[r], end = offs[r + 1];
    const int tid = threadIdx.x;
    const int wave = tid >> 6, lane = tid & 63;

    __shared__ float hlds[ST * EC];      // 64*32*4B = 8 KiB
    __shared__ int olds[ST];

    const float* __restrict__ Wr = W + ((size_t)r * DD + e0) * DD;

    for (int ts = start; ts < end; ts += ST) {
        const int tn = min(ST, end - ts);
        // stage this tile's head e-chunk (+ sample ids) into LDS
        for (int idx = tid; idx < tn * EC; idx += 256) {
            int s = idx >> 5;            // / EC
            int e = idx & (EC - 1);
            int gi = order[ts + s];
            if (e == 0) olds[s] = gi;
            hlds[idx] = head[(size_t)gi * DD + e0 + e];
        }
        __syncthreads();

        for (int sb = 0; sb < tn; sb += SB) {
            const int sn = min(SB, tn - sb);
            // load 8 tails' d-slice into registers (2KB/wave, coalesced)
            float4 t[SB][2];
            #pragma unroll
            for (int s = 0; s < SB; s++) {
                if (s < sn) {
                    const float4* tp =
                        (const float4*)(tail + (size_t)olds[sb + s] * DD + lane * 8);
                    t[s][0] = tp[0];
                    t[s][1] = tp[1];
                } else {
                    t[s][0] = make_float4(0.f, 0.f, 0.f, 0.f);
                    t[s][1] = make_float4(0.f, 0.f, 0.f, 0.f);
                }
            }
            float acc[SB];
            #pragma unroll
            for (int s = 0; s < SB; s++) acc[s] = 0.f;

            #pragma unroll
            for (int e = 0; e < EPW; e++) {
                const int er = wave * EPW + e;
                const float4* wp = (const float4*)(Wr + (size_t)er * DD + lane * 8);
                const float4 w0 = wp[0], w1 = wp[1];
                #pragma unroll
                for (int s = 0; s < SB; s++) {
                    float tmp = w0.x * t[s][0].x + w0.y * t[s][0].y +
                                w0.z * t[s][0].z + w0.w * t[s][0].w +
                                w1.x * t[s][1].x + w1.y * t[s][1].y +
                                w1.z * t[s][1].z + w1.w * t[s][1].w;
                    acc[s] = fmaf(hlds[(sb + s) * EC + er], tmp, acc[s]);
                }
            }

            #pragma unroll
            for (int s = 0; s < SB; s++) {
                float v = acc[s];
                #pragma unroll
                for (int off = 32; off; off >>= 1) v += __shfl_xor(v, off);
                if (lane == 0 && s < sn) atomicAdd(&out[olds[sb + s]], v);
            }
        }
        __syncthreads();
    }
}

extern "C" void kernel_launch(void* const* d_in, const int* in_sizes, int n_in,
                              void* d_out, int out_size, void* d_ws, size_t ws_size,
                              hipStream_t stream) {
    const float* head = (const float*)d_in[0];
    const float* tail = (const float*)d_in[1];
    const int*   rel  = (const int*)d_in[2];
    const float* W    = (const float*)d_in[3];
    const float* b    = (const float*)d_in[4];
    float* out = (float*)d_out;

    int*   wsi  = (int*)d_ws;
    float* wsf  = (float*)d_ws;
    int*   offs  = wsi + WS_OFFS;
    int*   order = wsi + WS_ORDER;
    float* bias  = wsf + WS_BIAS;

    k_bias<<<RR, 256, 0, stream>>>(b, bias);
    k_bucket<<<1, 256, 0, stream>>>(rel, bias, offs, order, out);
    k_main<<<RR * NCHUNK, 256, 0, stream>>>(head, tail, W, offs, order, out);
}

// Round 2
// 66.708 us; speedup vs baseline: 1.5440x; 1.5440x over previous
//
#include <hip/hip_runtime.h>

// Problem constants (match reference)
#define BB 2048   // batch
#define DD 512    // dim
#define RR 32     // relations

// Tiling: block = (relation r, e-chunk c of 32, sample-partition p of 4)
#define NCHUNK 16            // e-chunks per relation
#define EC (DD / NCHUNK)     // 32 e's per chunk
#define NWAVE 4              // 256 threads
#define EPW (EC / NWAVE)     // 8 e-rows per wave (held in registers)
#define SB 8                 // samples per group (register-resident tails)
#define SPLIT 4              // sample partitions per (r,c)

// ws layout (32-bit words)
#define WS_OFFS 0            // int offs[RR+1]
#define WS_ORDER 64          // int order[BB]

__global__ void k_bucket(const int* __restrict__ rel,
                         const float* __restrict__ b,
                         int* __restrict__ offs, int* __restrict__ order,
                         float* __restrict__ out) {
    __shared__ int cnt[RR], cur[RR];
    __shared__ float bs[RR];
    int tid = threadIdx.x;
    if (tid < RR) { cnt[tid] = 0; bs[tid] = 0.f; }
    __syncthreads();
    // bias row-sums: 8 threads per relation, 64 floats each, partial -> LDS atomic
    {
        int r = tid >> 3, sl = tid & 7;
        const float4* bp = (const float4*)(b + r * DD + sl * 64);
        float s = 0.f;
        #pragma unroll
        for (int j = 0; j < 16; j++) { float4 v = bp[j]; s += v.x + v.y + v.z + v.w; }
        atomicAdd(&bs[r], s);
    }
    for (int i = tid; i < BB; i += 256) atomicAdd(&cnt[rel[i]], 1);
    __syncthreads();
    if (tid == 0) {
        int acc = 0;
        for (int r = 0; r < RR; r++) { cur[r] = acc; offs[r] = acc; acc += cnt[r]; }
        offs[RR] = acc;
    }
    __syncthreads();
    for (int i = tid; i < BB; i += 256) {
        int r = rel[i];
        int pos = atomicAdd(&cur[r], 1);
        order[pos] = i;
        out[i] = bs[r];          // init output with relation bias-sum
    }
}

__launch_bounds__(256, 2)
__global__ void k_main(const float* __restrict__ head,
                       const float* __restrict__ tail,
                       const float* __restrict__ W,
                       const int* __restrict__ offs,
                       const int* __restrict__ order,
                       float* __restrict__ out) {
    // decode so the SPLIT partitions of one (r,c) land on the SAME XCD:
    // blockIdx = p*512 + rc  ->  xcd = blockIdx%8 = rc%8 for all p
    const int rc = blockIdx.x & 511;
    const int p  = blockIdx.x >> 9;
    const int r = rc >> 4;
    const int c = rc & (NCHUNK - 1);
    const int e0 = c * EC;
    const int start = offs[r], end = offs[r + 1];
    const int tid = threadIdx.x;
    const int wave = tid >> 6, lane = tid & 63;

    __shared__ float hlds[SB * EC];      // 8 samples x 32 e = 1 KiB
    __shared__ int olds[SB];
    __shared__ float sums[NWAVE][SB];

    // --- W held in registers: wave owns rows [e0 + wave*8, +8), lane owns d-slice [lane*8, +8)
    const float* Wr = W + ((size_t)r * DD + e0 + wave * EPW) * DD + lane * 8;
    float4 wv[EPW][2];
    #pragma unroll
    for (int e = 0; e < EPW; e++) {
        const float4* wp = (const float4*)(Wr + (size_t)e * DD);
        wv[e][0] = wp[0];
        wv[e][1] = wp[1];
    }

    for (int ts = start + p * SB; ts < end; ts += SPLIT * SB) {
        const int sn = min(SB, end - ts);
        // stage head e-chunk (8 samples x 32 e) + sample ids into LDS
        {
            int s = tid >> 5, e = tid & 31;
            int src = ts + s;
            int gi = order[src < end ? src : end - 1];
            if (e == 0) olds[s] = gi;
            hlds[tid] = (s < sn) ? head[(size_t)gi * DD + e0 + e] : 0.f;
        }
        __syncthreads();

        // tails -> registers (2 x float4 per sample per lane)
        float4 t[SB][2];
        #pragma unroll
        for (int s = 0; s < SB; s++) {
            if (s < sn) {
                const float4* tp = (const float4*)(tail + (size_t)olds[s] * DD + lane * 8);
                t[s][0] = tp[0];
                t[s][1] = tp[1];
            } else {
                t[s][0] = make_float4(0.f, 0.f, 0.f, 0.f);
                t[s][1] = make_float4(0.f, 0.f, 0.f, 0.f);
            }
        }

        float acc[SB];
        #pragma unroll
        for (int s = 0; s < SB; s++) acc[s] = 0.f;

        // pure-FMA inner loop: no global loads, 8 independent chains
        #pragma unroll
        for (int e = 0; e < EPW; e++) {
            const float4 w0 = wv[e][0], w1 = wv[e][1];
            #pragma unroll
            for (int s = 0; s < SB; s++) {
                float tmp = w0.x * t[s][0].x + w0.y * t[s][0].y +
                            w0.z * t[s][0].z + w0.w * t[s][0].w +
                            w1.x * t[s][1].x + w1.y * t[s][1].y +
                            w1.z * t[s][1].z + w1.w * t[s][1].w;
                acc[s] = fmaf(hlds[s * EC + wave * EPW + e], tmp, acc[s]);
            }
        }

        // lane butterfly, then cross-wave combine in LDS -> 1 atomic per sample
        #pragma unroll
        for (int s = 0; s < SB; s++) {
            float v = acc[s];
            #pragma unroll
            for (int off = 32; off; off >>= 1) v += __shfl_xor(v, off);
            if (lane == 0) sums[wave][s] = v;
        }
        __syncthreads();
        if (tid < SB && tid < sn) {
            float v = sums[0][tid] + sums[1][tid] + sums[2][tid] + sums[3][tid];
            atomicAdd(&out[olds[tid]], v);
        }
        __syncthreads();
    }
}

extern "C" void kernel_launch(void* const* d_in, const int* in_sizes, int n_in,
                              void* d_out, int out_size, void* d_ws, size_t ws_size,
                              hipStream_t stream) {
    const float* head = (const float*)d_in[0];
    const float* tail = (const float*)d_in[1];
    const int*   rel  = (const int*)d_in[2];
    const float* W    = (const float*)d_in[3];
    const float* b    = (const float*)d_in[4];
    float* out = (float*)d_out;

    int* wsi   = (int*)d_ws;
    int* offs  = wsi + WS_OFFS;
    int* order = wsi + WS_ORDER;

    k_bucket<<<1, 256, 0, stream>>>(rel, b, offs, order, out);
    k_main<<<SPLIT * RR * NCHUNK, 256, 0, stream>>>(head, tail, W, offs, order, out);
}

// Round 3
// 34.126 us; speedup vs baseline: 3.0181x; 1.9547x over previous
//
#include <hip/hip_runtime.h>

// Problem constants (match reference)
#define BB 2048   // batch
#define DD 512    // dim
#define RR 32     // relations

// GEMM tiling: block = (relation r, e-chunk nc of 128, d-chunk kc of 128)
#define NB 128               // e-range per block
#define KB 128               // d-range per block
#define KS 32                // d per K-step (MFMA K)
#define NKS (KB / KS)        // 4 K-steps
#define MT 96                // sample tile (covers n_r ~64+4sigma)
#define NWAVE 4

#define A_STRIDE (KB + 8)    // 136 bf16 -> 272 B row stride (breaks bank conflicts)
#define W_STRIDE (KS + 8)    // 40 bf16  -> 80 B row stride

// ws layout (32-bit words)
#define WS_OFFS 0            // int offs[RR+1]
#define WS_ORDER 64          // int order[BB]

typedef __attribute__((ext_vector_type(8))) short bf16x8;
typedef __attribute__((ext_vector_type(4))) float f32x4;

__device__ __forceinline__ unsigned short f2bf(float f) {
    unsigned u = __float_as_uint(f);
    return (unsigned short)((u + 0x7FFFu + ((u >> 16) & 1u)) >> 16);  // RNE
}
__device__ __forceinline__ unsigned pack2(float a, float b) {
    return (unsigned)f2bf(a) | ((unsigned)f2bf(b) << 16);
}

__global__ void k_bucket(const int* __restrict__ rel,
                         const float* __restrict__ b,
                         int* __restrict__ offs, int* __restrict__ order,
                         float* __restrict__ out) {
    __shared__ int cnt[RR], cur[RR];
    __shared__ float bs[RR];
    int tid = threadIdx.x;
    if (tid < RR) { cnt[tid] = 0; bs[tid] = 0.f; }
    __syncthreads();
    // bias row-sums: 8 threads per relation, 64 floats each -> LDS atomic
    {
        int r = tid >> 3, sl = tid & 7;
        const float4* bp = (const float4*)(b + r * DD + sl * 64);
        float s = 0.f;
        #pragma unroll
        for (int j = 0; j < 16; j++) { float4 v = bp[j]; s += v.x + v.y + v.z + v.w; }
        atomicAdd(&bs[r], s);
    }
    for (int i = tid; i < BB; i += 256) atomicAdd(&cnt[rel[i]], 1);
    __syncthreads();
    if (tid == 0) {
        int acc = 0;
        for (int r = 0; r < RR; r++) { cur[r] = acc; offs[r] = acc; acc += cnt[r]; }
        offs[RR] = acc;
    }
    __syncthreads();
    for (int i = tid; i < BB; i += 256) {
        int r = rel[i];
        int pos = atomicAdd(&cur[r], 1);
        order[pos] = i;
        out[i] = bs[r];          // init output with relation bias-sum
    }
}

__launch_bounds__(256, 2)
__global__ void k_main(const float* __restrict__ head,
                       const float* __restrict__ tail,
                       const float* __restrict__ W,
                       const int* __restrict__ offs,
                       const int* __restrict__ order,
                       float* __restrict__ out) {
    const int bid = blockIdx.x;
    const int r  = bid >> 4;
    const int nc = (bid >> 2) & 3;
    const int kc = bid & 3;
    const int e0 = nc * NB;
    const int k0 = kc * KB;
    const int start = offs[r], end = offs[r + 1];
    const int tid = threadIdx.x;
    const int wave = tid >> 6;
    const int lane = tid & 63;
    const int l15 = lane & 15, lg = lane >> 4;

    __shared__ unsigned short A_lds[MT * A_STRIDE];        // 25.5 KiB
    __shared__ unsigned short W_lds[2][NB * W_STRIDE];     // 20 KiB
    __shared__ float scpart[MT];
    __shared__ int olds[MT];

    const float* Wbase = W + ((size_t)r * DD + e0) * DD + k0;

    for (int ts = start; ts < end; ts += MT) {
        const int tn = min(MT, end - ts);
        if (tid < MT) scpart[tid] = 0.f;

        // ---- A stage: tail[tn x KB] fp32 -> bf16 LDS; pad rows zeroed
        #pragma unroll
        for (int i = 0; i < (MT * KB / 4) / 256; i++) {    // 12 iters
            int idx = i * 256 + tid;
            int row = idx >> 5;                            // KB/4 = 32 float4/row
            int fc  = idx & 31;
            float4 v = make_float4(0.f, 0.f, 0.f, 0.f);
            if (row < tn) {
                int gi = order[ts + row];
                if (fc == 0) olds[row] = gi;
                v = *(const float4*)(tail + (size_t)gi * DD + k0 + fc * 4);
            }
            unsigned* p = (unsigned*)&A_lds[row * A_STRIDE + fc * 4];
            p[0] = pack2(v.x, v.y);
            p[1] = pack2(v.z, v.w);
        }
        // ---- W step 0 -> regs
        float4 w0[4];
        #pragma unroll
        for (int j = 0; j < 4; j++) {
            int idx = j * 256 + tid;
            int row = idx >> 3, fc = idx & 7;              // 8 float4/row
            w0[j] = *(const float4*)(Wbase + (size_t)row * DD + fc * 4);
        }
        __syncthreads();
        #pragma unroll
        for (int j = 0; j < 4; j++) {
            int idx = j * 256 + tid;
            int row = idx >> 3, fc = idx & 7;
            unsigned* p = (unsigned*)&W_lds[0][row * W_STRIDE + fc * 4];
            p[0] = pack2(w0[j].x, w0[j].y);
            p[1] = pack2(w0[j].z, w0[j].w);
        }
        __syncthreads();

        f32x4 acc[6][2];
        #pragma unroll
        for (int m = 0; m < 6; m++)
            #pragma unroll
            for (int n2 = 0; n2 < 2; n2++)
                acc[m][n2] = (f32x4){0.f, 0.f, 0.f, 0.f};

        #pragma unroll
        for (int ks = 0; ks < NKS; ks++) {
            const int cur = ks & 1;
            // prefetch next W chunk into regs (HBM latency hides under MFMA)
            float4 wn[4];
            if (ks < NKS - 1) {
                #pragma unroll
                for (int j = 0; j < 4; j++) {
                    int idx = j * 256 + tid;
                    int row = idx >> 3, fc = idx & 7;
                    wn[j] = *(const float4*)(Wbase + (size_t)row * DD + (ks + 1) * KS + fc * 4);
                }
            }
            // B frags: lane l -> W[e = base+l15][k = 8*lg + j]
            bf16x8 bfr[2];
            #pragma unroll
            for (int n2 = 0; n2 < 2; n2++) {
                int e = wave * 32 + n2 * 16 + l15;
                bfr[n2] = *(const bf16x8*)&W_lds[cur][e * W_STRIDE + lg * 8];
            }
            #pragma unroll
            for (int m = 0; m < 6; m++) {
                bf16x8 af = *(const bf16x8*)&A_lds[(m * 16 + l15) * A_STRIDE + ks * KS + lg * 8];
                #pragma unroll
                for (int n2 = 0; n2 < 2; n2++)
                    acc[m][n2] = __builtin_amdgcn_mfma_f32_16x16x32_bf16(af, bfr[n2], acc[m][n2], 0, 0, 0);
            }
            __syncthreads();   // all waves done READING buf cur^1 (prev step) before overwrite
            if (ks < NKS - 1) {
                #pragma unroll
                for (int j = 0; j < 4; j++) {
                    int idx = j * 256 + tid;
                    int row = idx >> 3, fc = idx & 7;
                    unsigned* p = (unsigned*)&W_lds[cur ^ 1][row * W_STRIDE + fc * 4];
                    p[0] = pack2(wn[j].x, wn[j].y);
                    p[1] = pack2(wn[j].z, wn[j].w);
                }
            }
            __syncthreads();   // writes visible before next step's reads
        }

        // ---- epilogue: score_part[s] = sum_e acc[s,e] * head[s,e]
        // C layout: col(e) = l15, row(s) = 4*lg + q  (m89-verified)
        const int ebase = e0 + wave * 32;
        #pragma unroll
        for (int m = 0; m < 6; m++) {
            float v[4];
            #pragma unroll
            for (int q = 0; q < 4; q++) {
                int sl = m * 16 + lg * 4 + q;
                int si = min(sl, tn - 1);
                const float* hp = head + (size_t)olds[si] * DD + ebase + l15;
                float h0 = hp[0], h1 = hp[16];          // coalesced per quarter-wave
                v[q] = acc[m][0][q] * h0 + acc[m][1][q] * h1;  // pad rows: acc==0
            }
            #pragma unroll
            for (int q = 0; q < 4; q++) {
                #pragma unroll
                for (int off = 1; off < 16; off <<= 1)
                    v[q] += __shfl_xor(v[q], off);      // reduce over e (low 4 lane bits)
                if (l15 == 0) {
                    int sl = m * 16 + lg * 4 + q;
                    if (sl < tn) atomicAdd(&scpart[sl], v[q]);
                }
            }
        }
        __syncthreads();
        if (tid < tn) atomicAdd(out + olds[tid], scpart[tid]);
        __syncthreads();   // protect scpart/olds before next tile overwrites
    }
}

extern "C" void kernel_launch(void* const* d_in, const int* in_sizes, int n_in,
                              void* d_out, int out_size, void* d_ws, size_t ws_size,
                              hipStream_t stream) {
    const float* head = (const float*)d_in[0];
    const float* tail = (const float*)d_in[1];
    const int*   rel  = (const int*)d_in[2];
    const float* W    = (const float*)d_in[3];
    const float* b    = (const float*)d_in[4];
    float* out = (float*)d_out;

    int* wsi   = (int*)d_ws;
    int* offs  = wsi + WS_OFFS;
    int* order = wsi + WS_ORDER;

    k_bucket<<<1, 256, 0, stream>>>(rel, b, offs, order, out);
    k_main<<<RR * (DD / NB) * (DD / KB), 256, 0, stream>>>(head, tail, W, offs, order, out);
}